// Round 9
// baseline (382.702 us; speedup 1.0000x reference)
//
#include <hip/hip_runtime.h>

typedef short short8v __attribute__((ext_vector_type(8)));
typedef float f32x4  __attribute__((ext_vector_type(4)));

#define NP    81
#define P2    83
#define Y2    66
#define X2    66
#define PIX2  (Y2*X2)             // 4356 pixels per padded (y,x) plane
#define SLABE ((long)P2*PIX2*16)  // bf16 elems per (b,d) slab = 5,784,768
#define LDS_BYTES 73728           // 4608 chunks of 16B
#define WL2_SHORTS (14*4*16*8)    // 7168 shorts = 14336 B, [s][kg][n][e] weight frags

// round-to-nearest-even f32 -> bf16
__device__ __forceinline__ unsigned short f2bf(float f){
  union{float f; unsigned u;} v; v.f=f;
  return (unsigned short)((v.u + 0x7FFFu + ((v.u>>16)&1u))>>16);
}

// ---------------- zero halo borders: enumerate border pixels only ----------------
#define PERSLAB (2*PIX2 + 81*260)   // 29772 border pixels per slab
__global__ void zero_border(unsigned short* __restrict__ ws){
  int idx=blockIdx.x*256+threadIdx.x;
  if(idx>=8*PERSLAB) return;
  int slab=idx/PERSLAB;
  int r=idx-slab*PERSLAB;
  int p,y,x;
  if(r<2*PIX2){
    p=(r<PIX2)?0:(P2-1);
    int rr=(r<PIX2)?r:(r-PIX2);
    y=rr/X2; x=rr-y*X2;
  }else{
    int rr=r-2*PIX2;
    p=1+rr/260;
    int q=rr%260;
    if(q<66){ y=0; x=q; }
    else if(q<132){ y=Y2-1; x=q-66; }
    else { int t=q-132; y=1+(t>>1); x=(t&1)*(X2-1); }
  }
  long pix=(long)p*PIX2+(long)y*X2+x;
  uint4 z={0u,0u,0u,0u};
  uint4* dst=(uint4*)(ws+(long)slab*SLABE+pix*16);
  dst[0]=z; dst[1]=z;
}

// ---------------- correlation + leaky relu -> bf16 NHWC padded ----------------
// grid (64 y, 8 bd, 3 iseg), block (64,4).
// Wave (ty) owns 16 x-pixels (x = ty*16 + (lane&15)); lane>>4 = g-quad.
// In-wave ds_bpermute transpose -> lane-linear 8B stores = 512B contiguous/wave.
__global__ __launch_bounds__(256) void corr_kernel(
    const float* __restrict__ x1, const float* __restrict__ x2,
    unsigned short* __restrict__ ws)
{
  const int tx=threadIdx.x, xq=threadIdx.y;
  const int wq=tx>>4, xi=tx&15;
  const int x=xq*16+xi;
  const int y=blockIdx.x;
  const int bd=blockIdx.y, b=bd&1, d=bd>>1;
  const int dil=1<<d;                    // 1,2,4,8
  const int i0=blockIdx.z*3;
  const int g0=wq*4;
  const float* x1b = x1 + (long)b*128*4096;
  const float* x2b = x2 + (long)b*128*4096;
  float a1[8][4];
#pragma unroll
  for(int k=0;k<8;++k)
#pragma unroll
    for(int c=0;c<4;++c)
      a1[k][c]=x1b[(long)(k*16+g0+c)*4096 + y*64 + x];   // channel = k*16 + g
  char* sp=(char*)(ws+(long)bd*SLABE);
  const int srcaddr=((tx&3)*16+(tx>>2))*4;   // bpermute: dest lane l' pulls from lane (l'&3)*16+(l'>>2)
  for(int i=i0;i<i0+3;++i){
    const int yy=y+(i-4)*dil;
    const bool yok=(unsigned)yy<64u;
#pragma unroll
    for(int j=0;j<9;++j){
      const int xx=x+(j-4)*dil;
      float s0=0.f,s1=0.f,s2=0.f,s3=0.f;
      if(yok&&((unsigned)xx<64u)){
        const float* p2=x2b+yy*64+xx;
#pragma unroll
        for(int k=0;k<8;++k){
          s0=fmaf(a1[k][0],p2[(long)(k*16+g0+0)*4096],s0);
          s1=fmaf(a1[k][1],p2[(long)(k*16+g0+1)*4096],s1);
          s2=fmaf(a1[k][2],p2[(long)(k*16+g0+2)*4096],s2);
          s3=fmaf(a1[k][3],p2[(long)(k*16+g0+3)*4096],s3);
        }
      }
      ushort4 o;
      o.x=f2bf(s0>0.f?s0:0.1f*s0);
      o.y=f2bf(s1>0.f?s1:0.1f*s1);
      o.z=f2bf(s2>0.f?s2:0.1f*s2);
      o.w=f2bf(s3>0.f?s3:0.1f*s3);
      union{ushort4 u4; int w[2];} pk; pk.u4=o;
      int lo=__builtin_amdgcn_ds_bpermute(srcaddr,pk.w[0]);
      int hi=__builtin_amdgcn_ds_bpermute(srcaddr,pk.w[1]);
      const int p=i*9+j;
      // dest: pixel x'=xq*16+(tx>>2), quad tx&3 -> byte = base + tx*8 (lane-linear)
      char* dst=sp + ((long)(p+1)*PIX2+(long)(y+1)*X2+1+xq*16)*32 + tx*8;
      int2 v; v.x=lo; v.y=hi;
      *(int2*)dst=v;
    }
  }
}

// ---------------- conv3d as implicit GEMM on MFMA + bias/BN/ReLU ----------------
// grid (9 ptile, 64 y, 8 bd), block 256 (4 waves, wave owns x-quarter).
// A tile: [11 pp][3 yy][66 xx][16 gi] bf16, staged linearly via global_load_lds,
// XOR-swizzled (bits[6:4] ^= bits[9:7]) source for conflict-free ds_read_b128.
// B: weight frags pre-arranged in LDS as [s][lane] -> lane-linear conflict-free read.
// Staging split: iters 4..17 (bytes>=16K, no wl2 alias) issued FIRST and kept in
// flight through the weight phase (lgkmcnt-only barriers); iters 0..3 last.
__global__ __launch_bounds__(256,2) void conv_mfma(
    const unsigned short* __restrict__ ws,
    const float* __restrict__ w_all, const float* __restrict__ bias_all,
    const float* __restrict__ gamma_all, const float* __restrict__ beta_all,
    const float* __restrict__ mean_all, const float* __restrict__ var_all,
    float* __restrict__ out)
{
  __shared__ uint4 smem4[LDS_BYTES/16];
  const int tid=threadIdx.x, lane=tid&63, wv=tid>>6;
  const int bz=blockIdx.z, d=bz>>1, b=bz&1;
  const int p0=blockIdx.x*9, y0=blockIdx.y;
  const unsigned short* slab=ws+(long)bz*SLABE;
  char* smemb=(char*)smem4;

#define STAGE_IT(it_) {                                                        \
    int slot=(it_)*256+tid;                                                    \
    int sc=slot>4355?4355:slot;                                                \
    unsigned S=(unsigned)sc*16u;                                               \
    unsigned L=S^(((S>>7)&7u)<<4);                                             \
    unsigned pix=L>>5, ck=(L>>4)&1u;                                           \
    unsigned pp=pix/198u, r=pix-pp*198u;                                       \
    const char* gp=(const char*)slab                                           \
      + ((long)(p0+(int)pp)*PIX2+(long)y0*X2+r)*32 + ck*16;                    \
    char* lp=smemb+((it_)*256+(tid&~63))*16;                                   \
    __builtin_amdgcn_global_load_lds(                                          \
      (const __attribute__((address_space(1))) void*)gp,                       \
      (__attribute__((address_space(3))) void*)lp, 16, 0, 0); }

  // 1) bulk staging first (LDS bytes 16384..73727, disjoint from wl2)
#pragma unroll
  for(int it=4; it<18; ++it) STAGE_IT(it)

  // 2) weight phase under lgkmcnt-only barriers (staging stays in flight)
  unsigned short* wl2=(unsigned short*)smem4;   // first 14336 bytes
  for(int idx=tid; idx<WL2_SHORTS; idx+=256) wl2[idx]=0;
  asm volatile("s_waitcnt lgkmcnt(0)" ::: "memory");
  __builtin_amdgcn_s_barrier();
  const float* wd=w_all+(long)d*16*16*27;
  for(int idx=tid; idx<16*432; idx+=256){
    int go=idx/432, r=idx-go*432, gi=r/27, tap=r-gi*27;
    int s=tap>>1, kg=(tap&1)*2+(gi>>3), e=gi&7;
    wl2[((s*4+kg)*16+go)*8+e]=f2bf(wd[(go*16+gi)*27+tap]);
  }
  asm volatile("s_waitcnt lgkmcnt(0)" ::: "memory");
  __builtin_amdgcn_s_barrier();
  short8v bfr[14];
#pragma unroll
  for(int s=0;s<14;++s) bfr[s]=*(const short8v*)(wl2+(s*64+lane)*8);  // lane-linear: conflict-free
  asm volatile("s_waitcnt lgkmcnt(0)" ::: "memory");
  __builtin_amdgcn_s_barrier();                 // all bfr reads done before overwrite

  // 3) stage the wl2-aliased region (LDS bytes 0..16383)
#pragma unroll
  for(int it=0; it<4; ++it) STAGE_IT(it)
  __syncthreads();                              // full vmcnt+lgkm drain: tile ready

  const int n=lane&15, kg=lane>>4, chunk=kg&1, hi=kg>>1;
  const float scl=gamma_all[d*16+n]*rsqrtf(var_all[d*16+n]+1e-5f);
  const float ofs=(bias_all[d*16+n]-mean_all[d*16+n])*scl+beta_all[d*16+n];

  const char* sm=(const char*)smem4;
  const int x0=wv*16;
  const int mrow0=kg*4;

#pragma unroll
  for(int pg=0; pg<9; pg+=3){
    f32x4 ac0={0,0,0,0},ac1={0,0,0,0},ac2={0,0,0,0};
    const unsigned LB0=((pg+0)*198+x0+n)*32+chunk*16;
    const unsigned LB1=((pg+1)*198+x0+n)*32+chunk*16;
    const unsigned LB2=((pg+2)*198+x0+n)*32+chunk*16;
#pragma unroll
    for(int s=0;s<14;++s){
      const int t0=2*s, t1v=2*s+1;
      const int o0=((t0/9)*198+((t0%9)/3)*66+(t0%3))*32;
      const int o1=(t1v>26)?0:(((t1v/9)*198+((t1v%9)/3)*66+(t1v%3))*32);
      const int osel=hi?o1:o0;             // upper lane-half holds tap 2s+1
      unsigned L,S_;
      L=LB0+osel; S_=L^(((L>>7)&7u)<<4);
      short8v a0=*(const short8v*)(sm+S_);
      L=LB1+osel; S_=L^(((L>>7)&7u)<<4);
      short8v a1v=*(const short8v*)(sm+S_);
      L=LB2+osel; S_=L^(((L>>7)&7u)<<4);
      short8v a2v=*(const short8v*)(sm+S_);
      ac0=__builtin_amdgcn_mfma_f32_16x16x32_bf16(a0 ,bfr[s],ac0,0,0,0);
      ac1=__builtin_amdgcn_mfma_f32_16x16x32_bf16(a1v,bfr[s],ac1,0,0,0);
      ac2=__builtin_amdgcn_mfma_f32_16x16x32_bf16(a2v,bfr[s],ac2,0,0,0);
    }
#pragma unroll
    for(int jj=0;jj<3;++jj){
      f32x4 a=(jj==0)?ac0:((jj==1)?ac1:ac2);
      const int p=p0+pg+jj;
      float* ob=out+(((long)(b*64+d*16+n)*81+p)*4096)+y0*64+x0+mrow0;
#pragma unroll
      for(int rr=0;rr<4;++rr){
        float vv=fmaf(a[rr],scl,ofs);
        ob[rr]=vv>0.f?vv:0.f;
      }
    }
  }
#undef STAGE_IT
}

extern "C" void kernel_launch(void* const* d_in, const int* in_sizes, int n_in,
                              void* d_out, int out_size, void* d_ws, size_t ws_size,
                              hipStream_t stream) {
  const float* x    = (const float*)d_in[0];
  const float* nbx  = (const float*)d_in[1];
  const float* cw   = (const float*)d_in[2];
  const float* cbia = (const float*)d_in[3];
  const float* gam  = (const float*)d_in[4];
  const float* bet  = (const float*)d_in[5];
  const float* mea  = (const float*)d_in[6];
  const float* var  = (const float*)d_in[7];
  float* out = (float*)d_out;
  unsigned short* ws16 = (unsigned short*)d_ws;   // 8 slabs * 11.57 MB = 92.6 MB

  zero_border<<<dim3((8*PERSLAB+255)/256),dim3(256),0,stream>>>(ws16);
  corr_kernel<<<dim3(64,8,3),dim3(64,4),0,stream>>>(x,nbx,ws16);
  conv_mfma<<<dim3(9,64,8),dim3(256),0,stream>>>(ws16,cw,cbia,gam,bet,mea,var,out);
}